// Round 16
// baseline (2083.502 us; speedup 1.0000x reference)
//
#include <hip/hip_runtime.h>
#include <cstdint>
#include <cstddef>
#include <cmath>

#define DI __device__ __forceinline__
typedef float f32x4 __attribute__((ext_vector_type(4)));
typedef __bf16 bf16x8 __attribute__((ext_vector_type(8)));
typedef unsigned short u16;
typedef unsigned int u32;

static constexpr int TKN = 4096, SEQ = 2048, DIM = 2048, NH = 16;

DI u16 f2bf(float f) {
  union { float f; u32 u; } v; v.f = f;
  u32 r = v.u + 0x7fffu + ((v.u >> 16) & 1u);
  return (u16)(r >> 16);
}
DI float bf2f(u16 h) {
  union { u32 u; float f; } v; v.u = ((u32)h) << 16;
  return v.f;
}
DI f32x4 mfma16(bf16x8 a, bf16x8 b, f32x4 c) {
  return __builtin_amdgcn_mfma_f32_16x16x32_bf16(a, b, c, 0, 0, 0);
}
DI void gld16(const u16* g, u16* l) {
  __builtin_amdgcn_global_load_lds((const __attribute__((address_space(1))) u32*)g,
                                   (__attribute__((address_space(3))) u32*)l, 16, 0, 0);
}

enum { EF_F32 = 0, EF_BF16 = 1, EF_RES = 2, EF_KV = 3, EF_SILU = 4, EF_QROPE = 6 };
enum { AM_DIR = 0, AM_LIST = 1, AM_OFF = 2, AM_TIL = 3 };

// ================= unified m97-style GEMM (T2-swizzled LDS) =================
template<int EPI, int AMODE, int NSEG>
__global__ __launch_bounds__(256)
void gemm_f(const u16* __restrict__ A, const u16* __restrict__ B, void* __restrict__ C,
            int M, int N, int K, size_t apl, size_t bpl,
            const int* __restrict__ list, const int* __restrict__ basep,
            const int* __restrict__ counts,
            const void* __restrict__ aux, const float* __restrict__ gws,
            u16* __restrict__ kd0, u16* __restrict__ kd1, u16* __restrict__ vT,
            const float* __restrict__ cosT, const int* __restrict__ tb)
{
  constexpr int BM = 128, BK = 64;
  __shared__ __align__(16) u16 As[BM * BK];
  __shared__ __align__(16) u16 Bs[BM * BK];
  int rowbase = 0;
  int m0, n0;
  if (AMODE == AM_TIL) {
    int ntile = N >> 7;
    int u = blockIdx.x / ntile;
    if (u >= tb[12]) return;
    n0 = (blockIdx.x - u * ntile) << 7;
    int e = 0;
    #pragma unroll
    for (int k = 0; k < 11; k++) if (tb[k + 1] <= u) e = k + 1;
    M = counts[e];
    rowbase = basep[e];
    m0 = (u - tb[e]) << 7;
    B += (size_t)e * (size_t)N * K;
  } else if (AMODE != AM_DIR) {
    int z = blockIdx.z;
    M = counts[z];
    rowbase = basep[z];
    B += (size_t)z * (size_t)N * K;
    m0 = blockIdx.x * BM; n0 = blockIdx.y * BM;
    if (m0 >= M) return;
  } else {
    m0 = blockIdx.x * BM; n0 = blockIdx.y * BM;
    if (m0 >= M) return;
  }
  int tid = threadIdx.x, lane = tid & 63, wid = tid >> 6;
  int wm = (wid >> 1) * 64, wn = (wid & 1) * 64;
  int lr = lane & 15, lk = (lane >> 4) * 8;

  const u16* asrc[4];
  const u16* bsrc[4];
  int l8 = lane >> 3, c8 = ((lane & 7) ^ l8) * 8;
  #pragma unroll
  for (int i = 0; i < 4; i++) {
    int chunk = wid * 4 + i;
    int ra = m0 + chunk * 8 + l8;
    size_t rowidx;
    if (AMODE == AM_LIST)      rowidx = (size_t)list[rowbase + (ra < M ? ra : 0)];
    else if (AMODE == AM_OFF || AMODE == AM_TIL)
                               rowidx = (size_t)(rowbase + (ra < M ? ra : 0));
    else                       rowidx = (size_t)ra;
    asrc[i] = A + rowidx * (size_t)K + c8;
    int rb = n0 + chunk * 8 + l8;
    if (rb >= N) rb = N - 1;
    bsrc[i] = B + (size_t)rb * K + c8;
  }

  f32x4 acc[4][4] = {};
  int sw = lr & 7;
  #pragma unroll 1
  for (int s = 0; s < NSEG; s++) {
    int sa = (s == 4) ? 2 : (s & 1);          // {0,1,0,1,2,0}
    int sb = (s == 5) ? 2 : ((s >> 1) & 1);   // {0,0,1,1,0,2}
    size_t ao = (size_t)sa * apl, bo = (size_t)sb * bpl;
    for (int kt = 0; kt < K; kt += BK) {
      #pragma unroll
      for (int i = 0; i < 4; i++) {
        gld16(asrc[i] + ao + kt, &As[(wid * 4 + i) * 512]);
        gld16(bsrc[i] + bo + kt, &Bs[(wid * 4 + i) * 512]);
      }
      __syncthreads();
      #pragma unroll
      for (int ko = 0; ko < BK; ko += 32) {
        bf16x8 af[4], bv[4];
        int sl = ((((ko + lk) >> 3) ^ sw) << 3);
        #pragma unroll
        for (int i = 0; i < 4; i++)
          af[i] = *(const bf16x8*)(&As[(wm + i * 16 + lr) * 64 + sl]);
        #pragma unroll
        for (int j = 0; j < 4; j++)
          bv[j] = *(const bf16x8*)(&Bs[(wn + j * 16 + lr) * 64 + sl]);
        #pragma unroll
        for (int i = 0; i < 4; i++)
          #pragma unroll
          for (int j = 0; j < 4; j++)
            acc[i][j] = mfma16(af[i], bv[j], acc[i][j]);
      }
      __syncthreads();
    }
  }

  int og = (lane >> 4) * 4;
  if (EPI == EF_KV) {
    if (((n0 >> 7) & 1) == 0) {
      #pragma unroll
      for (int i = 0; i < 4; i++)
        #pragma unroll
        for (int p = 0; p < 4; p++) {
          int r = m0 + wm + i * 16 + og + p;
          #pragma unroll
          for (int j = 0; j < 4; j++) {
            int c = n0 + wn + j * 16 + lr;
            float v = acc[i][j][p];
            int hd = c >> 8, cc = c & 127;
            u16 b0 = f2bf(v);
            u16 b1 = f2bf(v - bf2f(b0));
            size_t base = ((size_t)r * NH + hd) * 128 + cc;
            kd0[base] = b0; kd1[base] = b1;
          }
        }
    } else {
      constexpr size_t VPL = (size_t)32 * 128 * 2048;
      #pragma unroll
      for (int i = 0; i < 4; i++) {
        int r0 = m0 + wm + i * 16 + og;
        int bb = r0 >> 11, ss = r0 & 2047;
        #pragma unroll
        for (int j = 0; j < 4; j++) {
          int c = n0 + wn + j * 16 + lr;
          int hd = c >> 8, ccv = c & 127;
          ushort4 q0, q1, q2;
          #pragma unroll
          for (int p = 0; p < 4; p++) {
            float v = acc[i][j][p];
            u16 b0 = f2bf(v);
            float r1 = v - bf2f(b0);
            u16 b1 = f2bf(r1);
            u16 b2 = f2bf(r1 - bf2f(b1));
            ((u16*)&q0)[p] = b0; ((u16*)&q1)[p] = b1; ((u16*)&q2)[p] = b2;
          }
          size_t vb = ((size_t)((bb * 16 + hd) * 128 + ccv)) * 2048 + ss;
          *(ushort4*)(vT + vb) = q0;
          *(ushort4*)(vT + VPL + vb) = q1;
          *(ushort4*)(vT + 2 * VPL + vb) = q2;
        }
      }
    }
  } else {
    #pragma unroll
    for (int i = 0; i < 4; i++)
      #pragma unroll
      for (int p = 0; p < 4; p++) {
        int r = m0 + wm + i * 16 + og + p;
        if (EPI != EF_QROPE) { if (r >= M) continue; }
        size_t outr = (AMODE == AM_DIR) ? (size_t)r : (size_t)(rowbase + r);
        #pragma unroll
        for (int j = 0; j < 4; j++) {
          int c = n0 + wn + j * 16 + lr;
          float v = acc[i][j][p];
          if (EPI == EF_F32) {
            if (c < N) ((float*)C)[outr * N + c] = v;
          } else if (EPI == EF_BF16) {
            ((u16*)C)[outr * N + c] = f2bf(v);
          } else if (EPI == EF_RES) {
            ((float*)C)[outr * N + c] = v + ((const float*)aux)[outr * N + c];
          } else if (EPI == EF_SILU) {
            float t = bf2f(((const u16*)aux)[outr * N + c]);
            float sg = t / (1.f + __expf(-t));
            ((u16*)C)[outr * N + c] = f2bf(sg * v);
          } else if (EPI == EF_QROPE) {
            int wi = c % 192;
            float vo = v;
            if (wi >= 128) {
              float part = __shfl_xor(v, 1);
              int jj = (wi - 128) >> 1;
              int srow = r & (SEQ - 1);
              float cs = cosT[srow * 32 + jj];
              float sn = ((const float*)aux)[srow * 32 + jj];
              vo = (c & 1) ? (part * sn + v * cs) : (v * cs - part * sn);
            }
            u16 b0 = f2bf(vo);
            u16 b1 = f2bf(vo - bf2f(b0));
            kd0[outr * (size_t)N + c] = b0;
            kd1[outr * (size_t)N + c] = b1;
          }
        }
      }
  }
}

// ===== flash attention (R6 body; XCD-clustered block swizzle: same-bh on same XCD) =====
__global__ __launch_bounds__(256)
void attn3(const u16* __restrict__ q0p, const u16* __restrict__ q1p,
           const u16* __restrict__ k0p, const u16* __restrict__ k1p,
           const u16* __restrict__ kp0, const u16* __restrict__ kp1,
           const u16* __restrict__ vT, u16* __restrict__ o0, float scale)
{
  constexpr int KLD = 200, VLD = 40, PLD = 36;
  constexpr size_t VPL = (size_t)32 * 128 * 2048;
  constexpr size_t OPL = (size_t)TKN * DIM;
  __shared__ __align__(16) u16 Ks[2][32 * KLD];
  __shared__ __align__(16) u16 Vt[3][128 * VLD];
  __shared__ __align__(16) float Ps[4][16 * PLD];

  // T1: cluster the 16 q-tile blocks of one (b,h) on one XCD (id mod 8 constant)
  int id = blockIdx.x;
  int xcd = id & 7, slot = id >> 3;         // slot in [0,64)
  int bh = xcd + 8 * (slot >> 4);           // 16 blocks per bh, all == xcd (mod 8)
  int qtx = slot & 15;
  int b = bh >> 4, h = bh & 15;
  int tid = threadIdx.x, lane = tid & 63, wid = tid >> 6;
  int lr = lane & 15, lg = lane >> 4, lk = lg * 8;
  size_t tbase = (size_t)b * SEQ;
  const u16* vbase = vT + (size_t)bh * 128 * 2048;

  for (int half = 0; half < 2; half++) {
    int qt = half ? (31 - qtx) : qtx;
    int q0r = qt * 64;
    bf16x8 qf[2][6];
    {
      size_t qoff = (tbase + q0r + wid * 16 + lr) * (size_t)3072 + h * 192;
      #pragma unroll
      for (int kc = 0; kc < 6; kc++) {
        qf[0][kc] = *(const bf16x8*)(q0p + qoff + kc * 32 + lk);
        qf[1][kc] = *(const bf16x8*)(q1p + qoff + kc * 32 + lk);
      }
    }
    f32x4 oacc[8] = {};
    float mrow[4], lrow[4];
    #pragma unroll
    for (int p = 0; p < 4; p++) { mrow[p] = -1e30f; lrow[p] = 0.f; }

    int nkt = 2 * qt + 2;
    for (int kt = 0; kt < nkt; kt++) {
      __syncthreads();
      int kr0 = kt * 32;
      #pragma unroll
      for (int p = 0; p < 2; p++) {
        const u16* knp = p ? k1p : k0p;
        const u16* kpp = p ? kp1 : kp0;
        #pragma unroll
        for (int i = 0; i < 2; i++) {
          int vv = tid + i * 256, r = vv >> 4, cc8 = (vv & 15) * 8;
          int4 d = *(const int4*)(knp + ((tbase + kr0 + r) * (size_t)NH + h) * 128 + cc8);
          *(int4*)(&Ks[p][r * KLD + cc8]) = d;
        }
        {
          int r = tid >> 3, cc8 = (tid & 7) * 8;
          int4 d = *(const int4*)(kpp + (tbase + kr0 + r) * (size_t)64 + cc8);
          *(int4*)(&Ks[p][r * KLD + 128 + cc8]) = d;
        }
      }
      #pragma unroll
      for (int p = 0; p < 3; p++) {
        #pragma unroll
        for (int i = 0; i < 2; i++) {
          int vv = tid + i * 256, d = vv >> 2, cc8 = (vv & 3) * 8;
          int4 dd = *(const int4*)(vbase + p * VPL + (size_t)d * 2048 + kr0 + cc8);
          *(int4*)(&Vt[p][d * VLD + cc8]) = dd;
        }
      }
      __syncthreads();

      f32x4 sacc[2] = {};
      #pragma unroll
      for (int j = 0; j < 2; j++)
        #pragma unroll
        for (int kc = 0; kc < 6; kc++) {
          bf16x8 kf0 = *(const bf16x8*)(&Ks[0][(j * 16 + lr) * KLD + kc * 32 + lk]);
          bf16x8 kf1 = *(const bf16x8*)(&Ks[1][(j * 16 + lr) * KLD + kc * 32 + lk]);
          f32x4 t = sacc[j];
          t = mfma16(qf[0][kc], kf0, t);
          t = mfma16(qf[1][kc], kf0, t);
          t = mfma16(qf[0][kc], kf1, t);
          sacc[j] = t;
        }

      bool tail = (kt >= 2 * qt);
      float fsc[4];
      #pragma unroll
      for (int p = 0; p < 4; p++) {
        float s0 = sacc[0][p] * scale, s1 = sacc[1][p] * scale;
        if (tail) {
          int qrow = q0r + wid * 16 + lg * 4 + p;
          if (kr0 + lr > qrow) s0 = -1e30f;
          if (kr0 + 16 + lr > qrow) s1 = -1e30f;
        }
        float mx = fmaxf(s0, s1);
        #pragma unroll
        for (int off = 1; off < 16; off <<= 1) mx = fmaxf(mx, __shfl_xor(mx, off));
        float mnew = fmaxf(mrow[p], mx);
        fsc[p] = __expf(mrow[p] - mnew);
        float e0 = __expf(s0 - mnew), e1 = __expf(s1 - mnew);
        float ssum = e0 + e1;
        #pragma unroll
        for (int off = 1; off < 16; off <<= 1) ssum += __shfl_xor(ssum, off);
        lrow[p] = lrow[p] * fsc[p] + ssum;
        mrow[p] = mnew;
        Ps[wid][(lg * 4 + p) * PLD + lr] = e0;
        Ps[wid][(lg * 4 + p) * PLD + 16 + lr] = e1;
      }
      #pragma unroll
      for (int jf = 0; jf < 8; jf++) {
        f32x4 t = oacc[jf];
        t[0] *= fsc[0]; t[1] *= fsc[1]; t[2] *= fsc[2]; t[3] *= fsc[3];
        oacc[jf] = t;
      }

      f32x4 pva = *(const f32x4*)(&Ps[wid][lr * PLD + lk]);
      f32x4 pvb = *(const f32x4*)(&Ps[wid][lr * PLD + lk + 4]);
      union { u16 us[8]; bf16x8 v; } pa0u, pa1u;
      #pragma unroll
      for (int e = 0; e < 4; e++) {
        float va = pva[e];
        u16 b0 = f2bf(va); pa0u.us[e] = b0; pa1u.us[e] = f2bf(va - bf2f(b0));
        float vb = pvb[e];
        u16 c0 = f2bf(vb); pa0u.us[4 + e] = c0; pa1u.us[4 + e] = f2bf(vb - bf2f(c0));
      }

      #pragma unroll
      for (int jf = 0; jf < 8; jf++) {
        bf16x8 vf0 = *(const bf16x8*)(&Vt[0][(jf * 16 + lr) * VLD + lk]);
        bf16x8 vf1 = *(const bf16x8*)(&Vt[1][(jf * 16 + lr) * VLD + lk]);
        bf16x8 vf2 = *(const bf16x8*)(&Vt[2][(jf * 16 + lr) * VLD + lk]);
        f32x4 t = oacc[jf];
        t = mfma16(pa0u.v, vf0, t);
        t = mfma16(pa1u.v, vf0, t);
        t = mfma16(pa0u.v, vf1, t);
        t = mfma16(pa1u.v, vf1, t);
        t = mfma16(pa0u.v, vf2, t);
        oacc[jf] = t;
      }
    }

    #pragma unroll
    for (int p = 0; p < 4; p++) {
      float inv = 1.f / lrow[p];
      int qrow = q0r + wid * 16 + lg * 4 + p;
      size_t base = (tbase + qrow) * (size_t)DIM + h * 128;
      #pragma unroll
      for (int jf = 0; jf < 8; jf++) {
        float val = oacc[jf][p] * inv;
        u16 b0 = f2bf(val);
        float r1 = val - bf2f(b0);
        u16 b1 = f2bf(r1);
        u16 b2 = f2bf(r1 - bf2f(b1));
        size_t idx = base + jf * 16 + lr;
        o0[idx] = b0; o0[OPL + idx] = b1; o0[2 * OPL + idx] = b2;
      }
    }
  }
}

// ================= small kernels =================
__global__ __launch_bounds__(256)
void rmsnorm3(const float* __restrict__ x, const float* __restrict__ w, u16* __restrict__ out)
{
  __shared__ float sred[4];
  constexpr size_t PL = (size_t)TKN * DIM;
  int t = blockIdx.x, tid = threadIdx.x;
  const float* xp = x + (size_t)t * DIM;
  float vals[8], ss = 0.f;
  #pragma unroll
  for (int i = 0; i < 8; i++) { float v = xp[tid + i * 256]; vals[i] = v; ss += v * v; }
  #pragma unroll
  for (int off = 32; off > 0; off >>= 1) ss += __shfl_xor(ss, off);
  if ((tid & 63) == 0) sred[tid >> 6] = ss;
  __syncthreads();
  ss = sred[0] + sred[1] + sred[2] + sred[3];
  float rstd = 1.f / sqrtf(ss / (float)DIM + 1e-6f);
  #pragma unroll
  for (int i = 0; i < 8; i++) {
    int d = tid + i * 256;
    float v = vals[i] * rstd * w[d];
    u16 b0 = f2bf(v);
    float r1 = v - bf2f(b0);
    u16 b1 = f2bf(r1);
    u16 b2 = f2bf(r1 - bf2f(b1));
    size_t o = (size_t)t * DIM + d;
    out[o] = b0; out[PL + o] = b1; out[2 * PL + o] = b2;
  }
}

__global__ __launch_bounds__(256)
void split3(const float* __restrict__ src, u16* __restrict__ dst, size_t n, size_t pl)
{
  size_t i0 = ((size_t)blockIdx.x * 256 + threadIdx.x) * 4;
  size_t stride = (size_t)gridDim.x * 1024;
  for (size_t i = i0; i < n; i += stride) {
    float4 d = *(const float4*)(src + i);
    ushort4 b0, b1, b2; float r;
    b0.x = f2bf(d.x); r = d.x - bf2f(b0.x); b1.x = f2bf(r); b2.x = f2bf(r - bf2f(b1.x));
    b0.y = f2bf(d.y); r = d.y - bf2f(b0.y); b1.y = f2bf(r); b2.y = f2bf(r - bf2f(b1.y));
    b0.z = f2bf(d.z); r = d.z - bf2f(b0.z); b1.z = f2bf(r); b2.z = f2bf(r - bf2f(b1.z));
    b0.w = f2bf(d.w); r = d.w - bf2f(b0.w); b1.w = f2bf(r); b2.w = f2bf(r - bf2f(b1.w));
    *(ushort4*)(dst + i) = b0;
    *(ushort4*)(dst + pl + i) = b1;
    *(ushort4*)(dst + 2 * pl + i) = b2;
  }
}

__global__ __launch_bounds__(256)
void cvt1(const float* __restrict__ src, u16* __restrict__ dst, size_t n)
{
  size_t i0 = ((size_t)blockIdx.x * 256 + threadIdx.x) * 4;
  size_t stride = (size_t)gridDim.x * 1024;
  for (size_t i = i0; i < n; i += stride) {
    float4 d = *(const float4*)(src + i);
    ushort4 b;
    b.x = f2bf(d.x); b.y = f2bf(d.y); b.z = f2bf(d.z); b.w = f2bf(d.w);
    *(ushort4*)(dst + i) = b;
  }
}

// gather h2 rows into slot-major buffer (all 16384 slots — deterministic size)
__global__ __launch_bounds__(256)
void gather_h2(const u16* __restrict__ h2, const int* __restrict__ list,
               u16* __restrict__ h2g)
{
  int slot = blockIdx.x;
  int tok = list[slot];
  int4 d = *(const int4*)(h2 + (size_t)tok * DIM + threadIdx.x * 8);
  *(int4*)(h2g + (size_t)slot * DIM + threadIdx.x * 8) = d;
}

// out[t] += sum_s gw4[t,s] * yout[slotrow[t,s]]
__global__ __launch_bounds__(256)
void final_combine(float* __restrict__ out, const u16* __restrict__ yout,
                   const float* __restrict__ gw4, const int* __restrict__ slotrow)
{
  int t = blockIdx.x, tid = threadIdx.x;
  int r0 = slotrow[t * 4], r1 = slotrow[t * 4 + 1];
  int r2 = slotrow[t * 4 + 2], r3 = slotrow[t * 4 + 3];
  float w0 = gw4[t * 4], w1_ = gw4[t * 4 + 1], w2_ = gw4[t * 4 + 2], w3_ = gw4[t * 4 + 3];
  #pragma unroll
  for (int i = 0; i < 8; i++) {
    int d = tid + i * 256;
    size_t o = (size_t)t * DIM + d;
    out[o] += w0 * bf2f(yout[(size_t)r0 * DIM + d])
            + w1_ * bf2f(yout[(size_t)r1 * DIM + d])
            + w2_ * bf2f(yout[(size_t)r2 * DIM + d])
            + w3_ * bf2f(yout[(size_t)r3 * DIM + d]);
  }
}

__global__ __launch_bounds__(256)
void kv_split(const float* __restrict__ kvraw, const float* __restrict__ kvw,
              u16* __restrict__ c0, u16* __restrict__ kp0, u16* __restrict__ kp1,
              const float* __restrict__ cosT, const float* __restrict__ sinT)
{
  __shared__ float sred[4];
  constexpr size_t CPL = (size_t)TKN * 512;
  int t = blockIdx.x, tid = threadIdx.x;
  const float* xp = kvraw + (size_t)t * 576;
  float v0 = xp[tid], v1 = xp[tid + 256];
  float ss = v0 * v0 + v1 * v1;
  #pragma unroll
  for (int off = 32; off > 0; off >>= 1) ss += __shfl_xor(ss, off);
  if ((tid & 63) == 0) sred[tid >> 6] = ss;
  __syncthreads();
  ss = sred[0] + sred[1] + sred[2] + sred[3];
  float rstd = 1.f / sqrtf(ss / 512.f + 1e-6f);
  #pragma unroll
  for (int half = 0; half < 2; half++) {
    float v = (half ? v1 : v0) * rstd * kvw[tid + half * 256];
    u16 b0 = f2bf(v);
    float r1 = v - bf2f(b0);
    u16 b1 = f2bf(r1);
    u16 b2 = f2bf(r1 - bf2f(b1));
    size_t o = (size_t)t * 512 + tid + half * 256;
    c0[o] = b0; c0[CPL + o] = b1; c0[2 * CPL + o] = b2;
  }
  if (tid < 32) {
    int srow = t & (SEQ - 1);
    float a = xp[512 + tid * 2], bb = xp[512 + tid * 2 + 1];
    float cs = cosT[srow * 32 + tid], sn = sinT[srow * 32 + tid];
    float ra = a * cs - bb * sn, rb = a * sn + bb * cs;
    u16 a0 = f2bf(ra), a1 = f2bf(ra - bf2f(a0));
    u16 c0b = f2bf(rb), c1 = f2bf(rb - bf2f(c0b));
    kp0[(size_t)t * 64 + tid * 2] = a0;     kp1[(size_t)t * 64 + tid * 2] = a1;
    kp0[(size_t)t * 64 + tid * 2 + 1] = c0b; kp1[(size_t)t * 64 + tid * 2 + 1] = c1;
  }
}

__global__ __launch_bounds__(256)
void rope_table(float* __restrict__ cosT, float* __restrict__ sinT, const int* __restrict__ sp)
{
  int i = blockIdx.x * 256 + threadIdx.x;
  if (i >= SEQ * 32) return;
  int j = i & 31, srow = i >> 5;
  float pos = (float)(srow + sp[0]);
  float inv = powf(10000.f, -(float)(2 * j) / 64.f);
  cosT[i] = cosf(pos * inv);
  sinT[i] = sinf(pos * inv);
}

// gate_topk also emits h2 (bf16) — fuses rmsnorm1
__global__ __launch_bounds__(256)
void gate_topk(const float* __restrict__ first, const float* __restrict__ nw,
               const float* __restrict__ gwm, const float* __restrict__ gbias,
               int* __restrict__ idx, float* __restrict__ gw4, int* __restrict__ counts,
               u16* __restrict__ h2out)
{
  __shared__ float sred[4];
  __shared__ float sacc[12][4];
  int t = blockIdx.x, tid = threadIdx.x;
  const float* xp = first + (size_t)t * DIM;
  float vals[8], ss = 0.f;
  #pragma unroll
  for (int i = 0; i < 8; i++) { float v = xp[tid + i * 256]; vals[i] = v; ss += v * v; }
  #pragma unroll
  for (int off = 32; off > 0; off >>= 1) ss += __shfl_xor(ss, off);
  if ((tid & 63) == 0) sred[tid >> 6] = ss;
  __syncthreads();
  ss = sred[0] + sred[1] + sred[2] + sred[3];
  float rstd = 1.f / sqrtf(ss / (float)DIM + 1e-6f);
  float acc[12];
  #pragma unroll
  for (int e = 0; e < 12; e++) acc[e] = 0.f;
  #pragma unroll
  for (int i = 0; i < 8; i++) {
    int d = tid + i * 256;
    float v = vals[i] * rstd * nw[d];
    h2out[(size_t)t * DIM + d] = f2bf(v);
    #pragma unroll
    for (int e = 0; e < 12; e++) acc[e] += v * gwm[e * DIM + d];
  }
  #pragma unroll
  for (int e = 0; e < 12; e++) {
    float a = acc[e];
    #pragma unroll
    for (int off = 32; off > 0; off >>= 1) a += __shfl_xor(a, off);
    if ((tid & 63) == 0) sacc[e][tid >> 6] = a;
  }
  __syncthreads();
  if (tid == 0) {
    float g[12], sc[12];
    #pragma unroll
    for (int e = 0; e < 12; e++) {
      float s = sacc[e][0] + sacc[e][1] + sacc[e][2] + sacc[e][3];
      g[e] = 1.f / (1.f + __expf(-s));
      sc[e] = g[e] + gbias[e];
    }
    bool taken[12] = {};
    int sel[4];
    float wsum = 0.f;
    #pragma unroll
    for (int s4 = 0; s4 < 4; s4++) {
      float best = -1e38f; int bi = 0;
      for (int e = 0; e < 12; e++)
        if (!taken[e] && sc[e] > best) { best = sc[e]; bi = e; }
      taken[bi] = true; sel[s4] = bi; wsum += g[bi];
    }
    #pragma unroll
    for (int s4 = 0; s4 < 4; s4++) {
      idx[t * 4 + s4] = sel[s4];
      gw4[t * 4 + s4] = g[sel[s4]] / wsum;
      atomicAdd(&counts[sel[s4]], 1);
    }
  }
}

__global__ void prefix12(const int* __restrict__ counts, int* __restrict__ basep,
                         int* __restrict__ cursor, int* __restrict__ tb)
{
  if (threadIdx.x == 0) {
    int run = 0, trun = 0;
    for (int e = 0; e < 12; e++) {
      basep[e] = run; tb[e] = trun;
      run += counts[e];
      trun += (counts[e] + 127) >> 7;
      cursor[e] = 0;
    }
    tb[12] = trun;
  }
}

__global__ __launch_bounds__(256)
void fill_lists(const int* __restrict__ idx, const int* __restrict__ basep,
                int* __restrict__ cursor, int* __restrict__ list,
                const float* __restrict__ gw4, float* __restrict__ gws,
                int* __restrict__ slotrow)
{
  int t = blockIdx.x * 256 + threadIdx.x;
  if (t >= TKN) return;
  #pragma unroll
  for (int s = 0; s < 4; s++) {
    int e = idx[t * 4 + s];
    int pos = atomicAdd(&cursor[e], 1);
    list[basep[e] + pos] = t;
    gws[basep[e] + pos] = gw4[t * 4 + s];
    slotrow[t * 4 + s] = basep[e] + pos;
  }
}

// ================= launch =================
extern "C" void kernel_launch(void* const* d_in, const int* in_sizes, int n_in,
                              void* d_out, int out_size, void* d_ws, size_t ws_size,
                              hipStream_t stream)
{
  (void)in_sizes; (void)n_in; (void)out_size; (void)ws_size;
  const float* x      = (const float*)d_in[0];
  const int*   sp     = (const int*)d_in[1];
  const float* norm_w = (const float*)d_in[2];
  const float* wq     = (const float*)d_in[3];
  const float* wkv_a  = (const float*)d_in[4];
  const float* kvnw   = (const float*)d_in[5];
  const float* wkv_b  = (const float*)d_in[6];
  const float* wo     = (const float*)d_in[7];
  const float* gatew  = (const float*)d_in[8];
  const float* gateb  = (const float*)d_in[9];
  const float* w1     = (const float*)d_in[10];
  const float* w2     = (const float*)d_in[11];
  const float* w3     = (const float*)d_in[12];
  const float* sw1    = (const float*)d_in[13];
  const float* sw2    = (const float*)d_in[14];
  const float* sw3    = (const float*)d_in[15];
  float* out = (float*)d_out;
  char* ws = (char*)d_ws;

  // ---- arena (time-multiplexed) ----
  const size_t D0 = 0, D1 = 50331648ull, D2 = 100663296ull, D3 = 150994944ull;
  const size_t SM = 188743680ull;
  u16* hpl   = (u16*)(ws + D0);                       // 3 planes, pl 8388608
  u16* cpl   = (u16*)(ws + D0);                       // 3 planes, pl 2097152
  u16* wkvbp = (u16*)(ws + D0 + 12582912ull);         // 3 planes, pl 2097152
  u16* opl   = (u16*)(ws + D0);                       // 3 planes, pl 8388608
  u16* t1b   = (u16*)(ws + D0);
  u16* asb   = (u16*)(ws + D0 + 16777216ull);
  u16* qpl   = (u16*)(ws + D1);                       // 2 planes, pl 12582912
  u16* swp   = (u16*)(ws + D1 + 25165824ull);
  u16* vtp   = (u16*)(ws + D2);                       // 3 planes, pl 8388608
  float* firstb = (float*)(ws + D2);
  u16* h2b   = (u16*)(ws + D2 + 33554432ull);         // @134217728
  u16* wqp   = (u16*)(ws + D3);                       // 3 planes, pl 6291456
  u16* wkvap = (u16*)(ws + D3);                       // 3 planes, pl 1179648
  float* kvr = (float*)(ws + D3 + 7077888ull);
  u16* kpl0  = (u16*)(ws + D3);                       // 2 planes, pl 8388608
  u16* kpl1  = kpl0 + 8388608ull;
  u16* kpe0  = (u16*)(ws + D3 + 33554432ull);
  u16* kpe1  = kpe0 + 262144ull;
  u16* wop   = (u16*)(ws + D3);                       // 3 planes, pl 4194304
  // expert stage (deterministic sizes)
  u16* h2g   = (u16*)(ws + 0);                        //  67,108,864 B (16384x2048 bf16)
  u16* yout  = (u16*)(ws + 0);                        //  67,108,864 B (over h2g: dead after gate GEMM)
  u16* y1e   = (u16*)(ws + 67108864ull);              //  33,554,432 B
  u16* aee   = (u16*)(ws + 100663296ull);             //  33,554,432 B
  u16* wexp  = (u16*)(ws + 134217728ull);             //  50,331,648 B (ends 184,549,376)
  float* cosT = (float*)(ws + SM);
  float* sinT = (float*)(ws + SM + 262144ull);
  int*   idxb = (int*)(ws + SM + 524288ull);
  float* gw4b = (float*)(ws + SM + 589824ull);
  int*   listb= (int*)(ws + SM + 655360ull);
  float* gwsb = (float*)(ws + SM + 720896ull);
  int*   cntb = (int*)(ws + SM + 786432ull);
  int*   curb = (int*)(ws + SM + 786688ull);
  int*   baseb= (int*)(ws + SM + 786944ull);
  int*   tbb  = (int*)(ws + SM + 787200ull);
  int*   slotb= (int*)(ws + SM + 787456ull);          // 65,536 B

  const size_t PL_TD = (size_t)TKN * DIM;  // 8388608

  hipMemsetAsync(cntb, 0, 256, stream);
  rope_table<<<dim3(256), 256, 0, stream>>>(cosT, sinT, sp);
  rmsnorm3<<<dim3(TKN), 256, 0, stream>>>(x, norm_w, hpl);

  // q = h @ wq^T (fused RoPE + x2-split out); 3 products
  split3<<<dim3(1024), 256, 0, stream>>>(wq, wqp, (size_t)3072 * 2048, 6291456ull);
  gemm_f<EF_QROPE, AM_DIR, 3><<<dim3(32, 24), 256, 0, stream>>>(
      hpl, wqp, nullptr, TKN, 3072, 2048, PL_TD, 6291456ull,
      nullptr, nullptr, nullptr, sinT, nullptr, qpl, qpl + 12582912ull, nullptr, cosT, nullptr);

  // kv = h @ wkv_a^T (f32-grade, 6 products)
  split3<<<dim3(512), 256, 0, stream>>>(wkv_a, wkvap, (size_t)576 * 2048, 1179648ull);
  gemm_f<EF_F32, AM_DIR, 6><<<dim3(32, 5), 256, 0, stream>>>(
      hpl, wkvap, kvr, TKN, 576, 2048, PL_TD, 1179648ull,
      nullptr, nullptr, nullptr, nullptr, nullptr, nullptr, nullptr, nullptr, nullptr, nullptr);

  kv_split<<<dim3(TKN), 256, 0, stream>>>(kvr, kvnw, cpl, kpe0, kpe1, cosT, sinT);

  // k_nope/v = c @ wkv_b^T (split K planes + transposed V planes)
  split3<<<dim3(1024), 256, 0, stream>>>(wkv_b, wkvbp, (size_t)4096 * 512, 2097152ull);
  gemm_f<EF_KV, AM_DIR, 6><<<dim3(32, 32), 256, 0, stream>>>(
      cpl, wkvbp, nullptr, TKN, 4096, 512, 2097152ull, 2097152ull,
      nullptr, nullptr, nullptr, nullptr, nullptr, kpl0, kpl1, vtp, nullptr, nullptr);

  attn3<<<dim3(512), 256, 0, stream>>>(qpl, qpl + 12582912ull, kpl0, kpl1,
      kpe0, kpe1, vtp, opl, 1.f / sqrtf(192.f));

  // first = o @ wo^T + x
  split3<<<dim3(1024), 256, 0, stream>>>(wo, wop, (size_t)2048 * 2048, 4194304ull);
  gemm_f<EF_RES, AM_DIR, 6><<<dim3(32, 16), 256, 0, stream>>>(
      opl, wop, firstb, TKN, 2048, 2048, PL_TD, 4194304ull,
      nullptr, nullptr, nullptr, x, nullptr, nullptr, nullptr, nullptr, nullptr, nullptr);

  gate_topk<<<dim3(TKN), 256, 0, stream>>>(firstb, norm_w, gatew, gateb, idxb, gw4b, cntb, h2b);
  prefix12<<<dim3(1), 64, 0, stream>>>(cntb, baseb, curb, tbb);
  fill_lists<<<dim3(16), 256, 0, stream>>>(idxb, baseb, curb, listb, gw4b, gwsb, slotb);

  // shared expert (84-VGPR template); down-proj adds `first` (out = ys + first)
  cvt1<<<dim3(1024), 256, 0, stream>>>(sw1, swp, (size_t)2048 * 2048);
  cvt1<<<dim3(1024), 256, 0, stream>>>(sw3, swp + 4194304ull, (size_t)2048 * 2048);
  cvt1<<<dim3(1024), 256, 0, stream>>>(sw2, swp + 8388608ull, (size_t)2048 * 2048);
  gemm_f<EF_BF16, AM_DIR, 1><<<dim3(32, 16), 256, 0, stream>>>(
      h2b, swp, t1b, TKN, 2048, 2048, 0, 0,
      nullptr, nullptr, nullptr, nullptr, nullptr, nullptr, nullptr, nullptr, nullptr, nullptr);
  gemm_f<EF_SILU, AM_DIR, 1><<<dim3(32, 16), 256, 0, stream>>>(
      h2b, swp + 4194304ull, asb, TKN, 2048, 2048, 0, 0,
      nullptr, nullptr, nullptr, t1b, nullptr, nullptr, nullptr, nullptr, nullptr, nullptr);
  gemm_f<EF_RES, AM_DIR, 1><<<dim3(32, 16), 256, 0, stream>>>(
      asb, swp + 8388608ull, out, TKN, 2048, 2048, 0, 0,
      nullptr, nullptr, nullptr, firstb, nullptr, nullptr, nullptr, nullptr, nullptr, nullptr);

  // routed experts: tile-compacted 1-D grids; down-proj de-atomized
  gather_h2<<<dim3(TKN * 4), 256, 0, stream>>>(h2b, listb, h2g);
  cvt1<<<dim3(2048), 256, 0, stream>>>(w1, wexp, (size_t)12 * 1024 * 2048);
  gemm_f<EF_BF16, AM_TIL, 1><<<dim3(12 * 32 * 8), 256, 0, stream>>>(
      h2g, wexp, y1e, 0, 1024, 2048, 0, 0,
      listb, baseb, cntb, nullptr, nullptr, nullptr, nullptr, nullptr, nullptr, tbb);
  cvt1<<<dim3(2048), 256, 0, stream>>>(w3, wexp, (size_t)12 * 1024 * 2048);
  gemm_f<EF_SILU, AM_TIL, 1><<<dim3(12 * 32 * 8), 256, 0, stream>>>(
      h2g, wexp, aee, 0, 1024, 2048, 0, 0,
      listb, baseb, cntb, y1e, nullptr, nullptr, nullptr, nullptr, nullptr, tbb);
  cvt1<<<dim3(2048), 256, 0, stream>>>(w2, wexp, (size_t)12 * 2048 * 1024);
  gemm_f<EF_BF16, AM_TIL, 1><<<dim3(12 * 32 * 16), 256, 0, stream>>>(
      aee, wexp, yout, 0, 2048, 1024, 0, 0,
      listb, baseb, cntb, nullptr, nullptr, nullptr, nullptr, nullptr, nullptr, tbb);
  final_combine<<<dim3(TKN), 256, 0, stream>>>(out, yout, gw4b, slotb);
}

// Round 17
// 1977.206 us; speedup vs baseline: 1.0538x; 1.0538x over previous
//
#include <hip/hip_runtime.h>
#include <cstdint>
#include <cstddef>
#include <cmath>

#define DI __device__ __forceinline__
typedef float f32x4 __attribute__((ext_vector_type(4)));
typedef __bf16 bf16x8 __attribute__((ext_vector_type(8)));
typedef unsigned short u16;
typedef unsigned int u32;

static constexpr int TKN = 4096, SEQ = 2048, DIM = 2048, NH = 16;

DI u16 f2bf(float f) {
  union { float f; u32 u; } v; v.f = f;
  u32 r = v.u + 0x7fffu + ((v.u >> 16) & 1u);
  return (u16)(r >> 16);
}
DI float bf2f(u16 h) {
  union { u32 u; float f; } v; v.u = ((u32)h) << 16;
  return v.f;
}
DI f32x4 mfma16(bf16x8 a, bf16x8 b, f32x4 c) {
  return __builtin_amdgcn_mfma_f32_16x16x32_bf16(a, b, c, 0, 0, 0);
}
DI void gld16(const u16* g, u16* l) {
  __builtin_amdgcn_global_load_lds((const __attribute__((address_space(1))) u32*)g,
                                   (__attribute__((address_space(3))) u32*)l, 16, 0, 0);
}

enum { EF_F32 = 0, EF_BF16 = 1, EF_RES = 2, EF_KV = 3, EF_SILU = 4, EF_QROPE = 6 };
enum { AM_DIR = 0, AM_LIST = 1, AM_OFF = 2, AM_TIL = 3 };

// ================= unified m97-style GEMM (T2-swizzled LDS) =================
template<int EPI, int AMODE, int NSEG>
__global__ __launch_bounds__(256)
void gemm_f(const u16* __restrict__ A, const u16* __restrict__ B, void* __restrict__ C,
            int M, int N, int K, size_t apl, size_t bpl,
            const int* __restrict__ list, const int* __restrict__ basep,
            const int* __restrict__ counts,
            const void* __restrict__ aux, const float* __restrict__ gws,
            u16* __restrict__ kd0, u16* __restrict__ kd1, u16* __restrict__ vT,
            const float* __restrict__ cosT, const int* __restrict__ tb)
{
  constexpr int BM = 128, BK = 64;
  __shared__ __align__(16) u16 As[BM * BK];
  __shared__ __align__(16) u16 Bs[BM * BK];
  int rowbase = 0;
  int m0, n0;
  if (AMODE == AM_TIL) {
    int ntile = N >> 7;
    int u = blockIdx.x / ntile;
    if (u >= tb[12]) return;
    n0 = (blockIdx.x - u * ntile) << 7;
    int e = 0;
    #pragma unroll
    for (int k = 0; k < 11; k++) if (tb[k + 1] <= u) e = k + 1;
    M = counts[e];
    rowbase = basep[e];
    m0 = (u - tb[e]) << 7;
    B += (size_t)e * (size_t)N * K;
  } else if (AMODE != AM_DIR) {
    int z = blockIdx.z;
    M = counts[z];
    rowbase = basep[z];
    B += (size_t)z * (size_t)N * K;
    m0 = blockIdx.x * BM; n0 = blockIdx.y * BM;
    if (m0 >= M) return;
  } else {
    m0 = blockIdx.x * BM; n0 = blockIdx.y * BM;
    if (m0 >= M) return;
  }
  int tid = threadIdx.x, lane = tid & 63, wid = tid >> 6;
  int wm = (wid >> 1) * 64, wn = (wid & 1) * 64;
  int lr = lane & 15, lk = (lane >> 4) * 8;

  const u16* asrc[4];
  const u16* bsrc[4];
  int l8 = lane >> 3, c8 = ((lane & 7) ^ l8) * 8;
  #pragma unroll
  for (int i = 0; i < 4; i++) {
    int chunk = wid * 4 + i;
    int ra = m0 + chunk * 8 + l8;
    size_t rowidx;
    if (AMODE == AM_LIST)      rowidx = (size_t)list[rowbase + (ra < M ? ra : 0)];
    else if (AMODE == AM_OFF || AMODE == AM_TIL)
                               rowidx = (size_t)(rowbase + (ra < M ? ra : 0));
    else                       rowidx = (size_t)ra;
    asrc[i] = A + rowidx * (size_t)K + c8;
    int rb = n0 + chunk * 8 + l8;
    if (rb >= N) rb = N - 1;
    bsrc[i] = B + (size_t)rb * K + c8;
  }

  f32x4 acc[4][4] = {};
  int sw = lr & 7;
  #pragma unroll 1
  for (int s = 0; s < NSEG; s++) {
    int sa = (s == 4) ? 2 : (s & 1);          // {0,1,0,1,2,0}
    int sb = (s == 5) ? 2 : ((s >> 1) & 1);   // {0,0,1,1,0,2}
    size_t ao = (size_t)sa * apl, bo = (size_t)sb * bpl;
    for (int kt = 0; kt < K; kt += BK) {
      #pragma unroll
      for (int i = 0; i < 4; i++) {
        gld16(asrc[i] + ao + kt, &As[(wid * 4 + i) * 512]);
        gld16(bsrc[i] + bo + kt, &Bs[(wid * 4 + i) * 512]);
      }
      __syncthreads();
      #pragma unroll
      for (int ko = 0; ko < BK; ko += 32) {
        bf16x8 af[4], bv[4];
        int sl = ((((ko + lk) >> 3) ^ sw) << 3);
        #pragma unroll
        for (int i = 0; i < 4; i++)
          af[i] = *(const bf16x8*)(&As[(wm + i * 16 + lr) * 64 + sl]);
        #pragma unroll
        for (int j = 0; j < 4; j++)
          bv[j] = *(const bf16x8*)(&Bs[(wn + j * 16 + lr) * 64 + sl]);
        #pragma unroll
        for (int i = 0; i < 4; i++)
          #pragma unroll
          for (int j = 0; j < 4; j++)
            acc[i][j] = mfma16(af[i], bv[j], acc[i][j]);
      }
      __syncthreads();
    }
  }

  int og = (lane >> 4) * 4;
  if (EPI == EF_KV) {
    if (((n0 >> 7) & 1) == 0) {
      #pragma unroll
      for (int i = 0; i < 4; i++)
        #pragma unroll
        for (int p = 0; p < 4; p++) {
          int r = m0 + wm + i * 16 + og + p;
          #pragma unroll
          for (int j = 0; j < 4; j++) {
            int c = n0 + wn + j * 16 + lr;
            float v = acc[i][j][p];
            int hd = c >> 8, cc = c & 127;
            u16 b0 = f2bf(v);
            u16 b1 = f2bf(v - bf2f(b0));
            size_t base = ((size_t)r * NH + hd) * 128 + cc;
            kd0[base] = b0; kd1[base] = b1;
          }
        }
    } else {
      constexpr size_t VPL = (size_t)32 * 128 * 2048;
      #pragma unroll
      for (int i = 0; i < 4; i++) {
        int r0 = m0 + wm + i * 16 + og;
        int bb = r0 >> 11, ss = r0 & 2047;
        #pragma unroll
        for (int j = 0; j < 4; j++) {
          int c = n0 + wn + j * 16 + lr;
          int hd = c >> 8, ccv = c & 127;
          ushort4 q0, q1, q2;
          #pragma unroll
          for (int p = 0; p < 4; p++) {
            float v = acc[i][j][p];
            u16 b0 = f2bf(v);
            float r1 = v - bf2f(b0);
            u16 b1 = f2bf(r1);
            u16 b2 = f2bf(r1 - bf2f(b1));
            ((u16*)&q0)[p] = b0; ((u16*)&q1)[p] = b1; ((u16*)&q2)[p] = b2;
          }
          size_t vb = ((size_t)((bb * 16 + hd) * 128 + ccv)) * 2048 + ss;
          *(ushort4*)(vT + vb) = q0;
          *(ushort4*)(vT + VPL + vb) = q1;
          *(ushort4*)(vT + 2 * VPL + vb) = q2;
        }
      }
    }
  } else {
    #pragma unroll
    for (int i = 0; i < 4; i++)
      #pragma unroll
      for (int p = 0; p < 4; p++) {
        int r = m0 + wm + i * 16 + og + p;
        if (EPI != EF_QROPE) { if (r >= M) continue; }
        size_t outr = (AMODE == AM_DIR) ? (size_t)r : (size_t)(rowbase + r);
        #pragma unroll
        for (int j = 0; j < 4; j++) {
          int c = n0 + wn + j * 16 + lr;
          float v = acc[i][j][p];
          if (EPI == EF_F32) {
            if (c < N) ((float*)C)[outr * N + c] = v;
          } else if (EPI == EF_BF16) {
            ((u16*)C)[outr * N + c] = f2bf(v);
          } else if (EPI == EF_RES) {
            ((float*)C)[outr * N + c] = v + ((const float*)aux)[outr * N + c];
          } else if (EPI == EF_SILU) {
            float t = bf2f(((const u16*)aux)[outr * N + c]);
            float sg = t / (1.f + __expf(-t));
            ((u16*)C)[outr * N + c] = f2bf(sg * v);
          } else if (EPI == EF_QROPE) {
            int wi = c % 192;
            float vo = v;
            if (wi >= 128) {
              float part = __shfl_xor(v, 1);
              int jj = (wi - 128) >> 1;
              int srow = r & (SEQ - 1);
              float cs = cosT[srow * 32 + jj];
              float sn = ((const float*)aux)[srow * 32 + jj];
              vo = (c & 1) ? (part * sn + v * cs) : (v * cs - part * sn);
            }
            u16 b0 = f2bf(vo);
            u16 b1 = f2bf(vo - bf2f(b0));
            kd0[outr * (size_t)N + c] = b0;
            kd1[outr * (size_t)N + c] = b1;
          }
        }
      }
  }
}

// ===== flash attention (R6-exact proven structure: 297 us, 120 VGPR) =====
__global__ __launch_bounds__(256)
void attn3(const u16* __restrict__ q0p, const u16* __restrict__ q1p,
           const u16* __restrict__ k0p, const u16* __restrict__ k1p,
           const u16* __restrict__ kp0, const u16* __restrict__ kp1,
           const u16* __restrict__ vT, u16* __restrict__ o0, float scale)
{
  constexpr int KLD = 200, VLD = 40, PLD = 36;
  constexpr size_t VPL = (size_t)32 * 128 * 2048;
  constexpr size_t OPL = (size_t)TKN * DIM;
  __shared__ __align__(16) u16 Ks[2][32 * KLD];
  __shared__ __align__(16) u16 Vt[3][128 * VLD];
  __shared__ __align__(16) float Ps[4][16 * PLD];

  int bh = blockIdx.y;
  int b = bh >> 4, h = bh & 15;
  int tid = threadIdx.x, lane = tid & 63, wid = tid >> 6;
  int lr = lane & 15, lg = lane >> 4, lk = lg * 8;
  size_t tbase = (size_t)b * SEQ;
  const u16* vbase = vT + (size_t)bh * 128 * 2048;

  for (int half = 0; half < 2; half++) {
    int qt = half ? (31 - (int)blockIdx.x) : (int)blockIdx.x;
    int q0r = qt * 64;
    bf16x8 qf[2][6];
    {
      size_t qoff = (tbase + q0r + wid * 16 + lr) * (size_t)3072 + h * 192;
      #pragma unroll
      for (int kc = 0; kc < 6; kc++) {
        qf[0][kc] = *(const bf16x8*)(q0p + qoff + kc * 32 + lk);
        qf[1][kc] = *(const bf16x8*)(q1p + qoff + kc * 32 + lk);
      }
    }
    f32x4 oacc[8] = {};
    float mrow[4], lrow[4];
    #pragma unroll
    for (int p = 0; p < 4; p++) { mrow[p] = -1e30f; lrow[p] = 0.f; }

    int nkt = 2 * qt + 2;
    for (int kt = 0; kt < nkt; kt++) {
      __syncthreads();
      int kr0 = kt * 32;
      #pragma unroll
      for (int p = 0; p < 2; p++) {
        const u16* knp = p ? k1p : k0p;
        const u16* kpp = p ? kp1 : kp0;
        #pragma unroll
        for (int i = 0; i < 2; i++) {
          int vv = tid + i * 256, r = vv >> 4, cc8 = (vv & 15) * 8;
          int4 d = *(const int4*)(knp + ((tbase + kr0 + r) * (size_t)NH + h) * 128 + cc8);
          *(int4*)(&Ks[p][r * KLD + cc8]) = d;
        }
        {
          int r = tid >> 3, cc8 = (tid & 7) * 8;
          int4 d = *(const int4*)(kpp + (tbase + kr0 + r) * (size_t)64 + cc8);
          *(int4*)(&Ks[p][r * KLD + 128 + cc8]) = d;
        }
      }
      #pragma unroll
      for (int p = 0; p < 3; p++) {
        #pragma unroll
        for (int i = 0; i < 2; i++) {
          int vv = tid + i * 256, d = vv >> 2, cc8 = (vv & 3) * 8;
          int4 dd = *(const int4*)(vbase + p * VPL + (size_t)d * 2048 + kr0 + cc8);
          *(int4*)(&Vt[p][d * VLD + cc8]) = dd;
        }
      }
      __syncthreads();

      f32x4 sacc[2] = {};
      #pragma unroll
      for (int j = 0; j < 2; j++)
        #pragma unroll
        for (int kc = 0; kc < 6; kc++) {
          bf16x8 kf0 = *(const bf16x8*)(&Ks[0][(j * 16 + lr) * KLD + kc * 32 + lk]);
          bf16x8 kf1 = *(const bf16x8*)(&Ks[1][(j * 16 + lr) * KLD + kc * 32 + lk]);
          f32x4 t = sacc[j];
          t = mfma16(qf[0][kc], kf0, t);
          t = mfma16(qf[1][kc], kf0, t);
          t = mfma16(qf[0][kc], kf1, t);
          sacc[j] = t;
        }

      bool tail = (kt >= 2 * qt);
      float fsc[4];
      #pragma unroll
      for (int p = 0; p < 4; p++) {
        float s0 = sacc[0][p] * scale, s1 = sacc[1][p] * scale;
        if (tail) {
          int qrow = q0r + wid * 16 + lg * 4 + p;
          if (kr0 + lr > qrow) s0 = -1e30f;
          if (kr0 + 16 + lr > qrow) s1 = -1e30f;
        }
        float mx = fmaxf(s0, s1);
        #pragma unroll
        for (int off = 1; off < 16; off <<= 1) mx = fmaxf(mx, __shfl_xor(mx, off));
        float mnew = fmaxf(mrow[p], mx);
        fsc[p] = __expf(mrow[p] - mnew);
        float e0 = __expf(s0 - mnew), e1 = __expf(s1 - mnew);
        float ssum = e0 + e1;
        #pragma unroll
        for (int off = 1; off < 16; off <<= 1) ssum += __shfl_xor(ssum, off);
        lrow[p] = lrow[p] * fsc[p] + ssum;
        mrow[p] = mnew;
        Ps[wid][(lg * 4 + p) * PLD + lr] = e0;
        Ps[wid][(lg * 4 + p) * PLD + 16 + lr] = e1;
      }
      #pragma unroll
      for (int jf = 0; jf < 8; jf++) {
        f32x4 t = oacc[jf];
        t[0] *= fsc[0]; t[1] *= fsc[1]; t[2] *= fsc[2]; t[3] *= fsc[3];
        oacc[jf] = t;
      }

      f32x4 pva = *(const f32x4*)(&Ps[wid][lr * PLD + lk]);
      f32x4 pvb = *(const f32x4*)(&Ps[wid][lr * PLD + lk + 4]);
      union { u16 us[8]; bf16x8 v; } pa0u, pa1u;
      #pragma unroll
      for (int e = 0; e < 4; e++) {
        float va = pva[e];
        u16 b0 = f2bf(va); pa0u.us[e] = b0; pa1u.us[e] = f2bf(va - bf2f(b0));
        float vb = pvb[e];
        u16 c0 = f2bf(vb); pa0u.us[4 + e] = c0; pa1u.us[4 + e] = f2bf(vb - bf2f(c0));
      }

      #pragma unroll
      for (int jf = 0; jf < 8; jf++) {
        bf16x8 vf0 = *(const bf16x8*)(&Vt[0][(jf * 16 + lr) * VLD + lk]);
        bf16x8 vf1 = *(const bf16x8*)(&Vt[1][(jf * 16 + lr) * VLD + lk]);
        bf16x8 vf2 = *(const bf16x8*)(&Vt[2][(jf * 16 + lr) * VLD + lk]);
        f32x4 t = oacc[jf];
        t = mfma16(pa0u.v, vf0, t);
        t = mfma16(pa1u.v, vf0, t);
        t = mfma16(pa0u.v, vf1, t);
        t = mfma16(pa1u.v, vf1, t);
        t = mfma16(pa0u.v, vf2, t);
        oacc[jf] = t;
      }
    }

    #pragma unroll
    for (int p = 0; p < 4; p++) {
      float inv = 1.f / lrow[p];
      int qrow = q0r + wid * 16 + lg * 4 + p;
      size_t base = (tbase + qrow) * (size_t)DIM + h * 128;
      #pragma unroll
      for (int jf = 0; jf < 8; jf++) {
        float val = oacc[jf][p] * inv;
        u16 b0 = f2bf(val);
        float r1 = val - bf2f(b0);
        u16 b1 = f2bf(r1);
        u16 b2 = f2bf(r1 - bf2f(b1));
        size_t idx = base + jf * 16 + lr;
        o0[idx] = b0; o0[OPL + idx] = b1; o0[2 * OPL + idx] = b2;
      }
    }
  }
}

// ================= small kernels =================
__global__ __launch_bounds__(256)
void rmsnorm3(const float* __restrict__ x, const float* __restrict__ w, u16* __restrict__ out)
{
  __shared__ float sred[4];
  constexpr size_t PL = (size_t)TKN * DIM;
  int t = blockIdx.x, tid = threadIdx.x;
  const float* xp = x + (size_t)t * DIM;
  float vals[8], ss = 0.f;
  #pragma unroll
  for (int i = 0; i < 8; i++) { float v = xp[tid + i * 256]; vals[i] = v; ss += v * v; }
  #pragma unroll
  for (int off = 32; off > 0; off >>= 1) ss += __shfl_xor(ss, off);
  if ((tid & 63) == 0) sred[tid >> 6] = ss;
  __syncthreads();
  ss = sred[0] + sred[1] + sred[2] + sred[3];
  float rstd = 1.f / sqrtf(ss / (float)DIM + 1e-6f);
  #pragma unroll
  for (int i = 0; i < 8; i++) {
    int d = tid + i * 256;
    float v = vals[i] * rstd * w[d];
    u16 b0 = f2bf(v);
    float r1 = v - bf2f(b0);
    u16 b1 = f2bf(r1);
    u16 b2 = f2bf(r1 - bf2f(b1));
    size_t o = (size_t)t * DIM + d;
    out[o] = b0; out[PL + o] = b1; out[2 * PL + o] = b2;
  }
}

__global__ __launch_bounds__(256)
void split3(const float* __restrict__ src, u16* __restrict__ dst, size_t n, size_t pl)
{
  size_t i0 = ((size_t)blockIdx.x * 256 + threadIdx.x) * 4;
  size_t stride = (size_t)gridDim.x * 1024;
  for (size_t i = i0; i < n; i += stride) {
    float4 d = *(const float4*)(src + i);
    ushort4 b0, b1, b2; float r;
    b0.x = f2bf(d.x); r = d.x - bf2f(b0.x); b1.x = f2bf(r); b2.x = f2bf(r - bf2f(b1.x));
    b0.y = f2bf(d.y); r = d.y - bf2f(b0.y); b1.y = f2bf(r); b2.y = f2bf(r - bf2f(b1.y));
    b0.z = f2bf(d.z); r = d.z - bf2f(b0.z); b1.z = f2bf(r); b2.z = f2bf(r - bf2f(b1.z));
    b0.w = f2bf(d.w); r = d.w - bf2f(b0.w); b1.w = f2bf(r); b2.w = f2bf(r - bf2f(b1.w));
    *(ushort4*)(dst + i) = b0;
    *(ushort4*)(dst + pl + i) = b1;
    *(ushort4*)(dst + 2 * pl + i) = b2;
  }
}

__global__ __launch_bounds__(256)
void cvt1(const float* __restrict__ src, u16* __restrict__ dst, size_t n)
{
  size_t i0 = ((size_t)blockIdx.x * 256 + threadIdx.x) * 4;
  size_t stride = (size_t)gridDim.x * 1024;
  for (size_t i = i0; i < n; i += stride) {
    float4 d = *(const float4*)(src + i);
    ushort4 b;
    b.x = f2bf(d.x); b.y = f2bf(d.y); b.z = f2bf(d.z); b.w = f2bf(d.w);
    *(ushort4*)(dst + i) = b;
  }
}

// gather h2 rows into slot-major buffer (all 16384 slots — deterministic size)
__global__ __launch_bounds__(256)
void gather_h2(const u16* __restrict__ h2, const int* __restrict__ list,
               u16* __restrict__ h2g)
{
  int slot = blockIdx.x;
  int tok = list[slot];
  int4 d = *(const int4*)(h2 + (size_t)tok * DIM + threadIdx.x * 8);
  *(int4*)(h2g + (size_t)slot * DIM + threadIdx.x * 8) = d;
}

// out[t] += sum_s gw4[t,s] * yout[slotrow[t,s]]
__global__ __launch_bounds__(256)
void final_combine(float* __restrict__ out, const u16* __restrict__ yout,
                   const float* __restrict__ gw4, const int* __restrict__ slotrow)
{
  int t = blockIdx.x, tid = threadIdx.x;
  int r0 = slotrow[t * 4], r1 = slotrow[t * 4 + 1];
  int r2 = slotrow[t * 4 + 2], r3 = slotrow[t * 4 + 3];
  float w0 = gw4[t * 4], w1_ = gw4[t * 4 + 1], w2_ = gw4[t * 4 + 2], w3_ = gw4[t * 4 + 3];
  #pragma unroll
  for (int i = 0; i < 8; i++) {
    int d = tid + i * 256;
    size_t o = (size_t)t * DIM + d;
    out[o] += w0 * bf2f(yout[(size_t)r0 * DIM + d])
            + w1_ * bf2f(yout[(size_t)r1 * DIM + d])
            + w2_ * bf2f(yout[(size_t)r2 * DIM + d])
            + w3_ * bf2f(yout[(size_t)r3 * DIM + d]);
  }
}

__global__ __launch_bounds__(256)
void kv_split(const float* __restrict__ kvraw, const float* __restrict__ kvw,
              u16* __restrict__ c0, u16* __restrict__ kp0, u16* __restrict__ kp1,
              const float* __restrict__ cosT, const float* __restrict__ sinT)
{
  __shared__ float sred[4];
  constexpr size_t CPL = (size_t)TKN * 512;
  int t = blockIdx.x, tid = threadIdx.x;
  const float* xp = kvraw + (size_t)t * 576;
  float v0 = xp[tid], v1 = xp[tid + 256];
  float ss = v0 * v0 + v1 * v1;
  #pragma unroll
  for (int off = 32; off > 0; off >>= 1) ss += __shfl_xor(ss, off);
  if ((tid & 63) == 0) sred[tid >> 6] = ss;
  __syncthreads();
  ss = sred[0] + sred[1] + sred[2] + sred[3];
  float rstd = 1.f / sqrtf(ss / 512.f + 1e-6f);
  #pragma unroll
  for (int half = 0; half < 2; half++) {
    float v = (half ? v1 : v0) * rstd * kvw[tid + half * 256];
    u16 b0 = f2bf(v);
    float r1 = v - bf2f(b0);
    u16 b1 = f2bf(r1);
    u16 b2 = f2bf(r1 - bf2f(b1));
    size_t o = (size_t)t * 512 + tid + half * 256;
    c0[o] = b0; c0[CPL + o] = b1; c0[2 * CPL + o] = b2;
  }
  if (tid < 32) {
    int srow = t & (SEQ - 1);
    float a = xp[512 + tid * 2], bb = xp[512 + tid * 2 + 1];
    float cs = cosT[srow * 32 + tid], sn = sinT[srow * 32 + tid];
    float ra = a * cs - bb * sn, rb = a * sn + bb * cs;
    u16 a0 = f2bf(ra), a1 = f2bf(ra - bf2f(a0));
    u16 c0b = f2bf(rb), c1 = f2bf(rb - bf2f(c0b));
    kp0[(size_t)t * 64 + tid * 2] = a0;     kp1[(size_t)t * 64 + tid * 2] = a1;
    kp0[(size_t)t * 64 + tid * 2 + 1] = c0b; kp1[(size_t)t * 64 + tid * 2 + 1] = c1;
  }
}

__global__ __launch_bounds__(256)
void rope_table(float* __restrict__ cosT, float* __restrict__ sinT, const int* __restrict__ sp)
{
  int i = blockIdx.x * 256 + threadIdx.x;
  if (i >= SEQ * 32) return;
  int j = i & 31, srow = i >> 5;
  float pos = (float)(srow + sp[0]);
  float inv = powf(10000.f, -(float)(2 * j) / 64.f);
  cosT[i] = cosf(pos * inv);
  sinT[i] = sinf(pos * inv);
}

// gate_topk also emits h2 (bf16) — fuses rmsnorm1
__global__ __launch_bounds__(256)
void gate_topk(const float* __restrict__ first, const float* __restrict__ nw,
               const float* __restrict__ gwm, const float* __restrict__ gbias,
               int* __restrict__ idx, float* __restrict__ gw4, int* __restrict__ counts,
               u16* __restrict__ h2out)
{
  __shared__ float sred[4];
  __shared__ float sacc[12][4];
  int t = blockIdx.x, tid = threadIdx.x;
  const float* xp = first + (size_t)t * DIM;
  float vals[8], ss = 0.f;
  #pragma unroll
  for (int i = 0; i < 8; i++) { float v = xp[tid + i * 256]; vals[i] = v; ss += v * v; }
  #pragma unroll
  for (int off = 32; off > 0; off >>= 1) ss += __shfl_xor(ss, off);
  if ((tid & 63) == 0) sred[tid >> 6] = ss;
  __syncthreads();
  ss = sred[0] + sred[1] + sred[2] + sred[3];
  float rstd = 1.f / sqrtf(ss / (float)DIM + 1e-6f);
  float acc[12];
  #pragma unroll
  for (int e = 0; e < 12; e++) acc[e] = 0.f;
  #pragma unroll
  for (int i = 0; i < 8; i++) {
    int d = tid + i * 256;
    float v = vals[i] * rstd * nw[d];
    h2out[(size_t)t * DIM + d] = f2bf(v);
    #pragma unroll
    for (int e = 0; e < 12; e++) acc[e] += v * gwm[e * DIM + d];
  }
  #pragma unroll
  for (int e = 0; e < 12; e++) {
    float a = acc[e];
    #pragma unroll
    for (int off = 32; off > 0; off >>= 1) a += __shfl_xor(a, off);
    if ((tid & 63) == 0) sacc[e][tid >> 6] = a;
  }
  __syncthreads();
  if (tid == 0) {
    float g[12], sc[12];
    #pragma unroll
    for (int e = 0; e < 12; e++) {
      float s = sacc[e][0] + sacc[e][1] + sacc[e][2] + sacc[e][3];
      g[e] = 1.f / (1.f + __expf(-s));
      sc[e] = g[e] + gbias[e];
    }
    bool taken[12] = {};
    int sel[4];
    float wsum = 0.f;
    #pragma unroll
    for (int s4 = 0; s4 < 4; s4++) {
      float best = -1e38f; int bi = 0;
      for (int e = 0; e < 12; e++)
        if (!taken[e] && sc[e] > best) { best = sc[e]; bi = e; }
      taken[bi] = true; sel[s4] = bi; wsum += g[bi];
    }
    #pragma unroll
    for (int s4 = 0; s4 < 4; s4++) {
      idx[t * 4 + s4] = sel[s4];
      gw4[t * 4 + s4] = g[sel[s4]] / wsum;
      atomicAdd(&counts[sel[s4]], 1);
    }
  }
}

__global__ void prefix12(const int* __restrict__ counts, int* __restrict__ basep,
                         int* __restrict__ cursor, int* __restrict__ tb)
{
  if (threadIdx.x == 0) {
    int run = 0, trun = 0;
    for (int e = 0; e < 12; e++) {
      basep[e] = run; tb[e] = trun;
      run += counts[e];
      trun += (counts[e] + 127) >> 7;
      cursor[e] = 0;
    }
    tb[12] = trun;
  }
}

__global__ __launch_bounds__(256)
void fill_lists(const int* __restrict__ idx, const int* __restrict__ basep,
                int* __restrict__ cursor, int* __restrict__ list,
                const float* __restrict__ gw4, float* __restrict__ gws,
                int* __restrict__ slotrow)
{
  int t = blockIdx.x * 256 + threadIdx.x;
  if (t >= TKN) return;
  #pragma unroll
  for (int s = 0; s < 4; s++) {
    int e = idx[t * 4 + s];
    int pos = atomicAdd(&cursor[e], 1);
    list[basep[e] + pos] = t;
    gws[basep[e] + pos] = gw4[t * 4 + s];
    slotrow[t * 4 + s] = basep[e] + pos;
  }
}

// ================= launch =================
extern "C" void kernel_launch(void* const* d_in, const int* in_sizes, int n_in,
                              void* d_out, int out_size, void* d_ws, size_t ws_size,
                              hipStream_t stream)
{
  (void)in_sizes; (void)n_in; (void)out_size; (void)ws_size;
  const float* x      = (const float*)d_in[0];
  const int*   sp     = (const int*)d_in[1];
  const float* norm_w = (const float*)d_in[2];
  const float* wq     = (const float*)d_in[3];
  const float* wkv_a  = (const float*)d_in[4];
  const float* kvnw   = (const float*)d_in[5];
  const float* wkv_b  = (const float*)d_in[6];
  const float* wo     = (const float*)d_in[7];
  const float* gatew  = (const float*)d_in[8];
  const float* gateb  = (const float*)d_in[9];
  const float* w1     = (const float*)d_in[10];
  const float* w2     = (const float*)d_in[11];
  const float* w3     = (const float*)d_in[12];
  const float* sw1    = (const float*)d_in[13];
  const float* sw2    = (const float*)d_in[14];
  const float* sw3    = (const float*)d_in[15];
  float* out = (float*)d_out;
  char* ws = (char*)d_ws;

  // ---- arena (time-multiplexed) ----
  const size_t D0 = 0, D1 = 50331648ull, D2 = 100663296ull, D3 = 150994944ull;
  const size_t SM = 188743680ull;
  u16* hpl   = (u16*)(ws + D0);                       // 3 planes, pl 8388608
  u16* cpl   = (u16*)(ws + D0);                       // 3 planes, pl 2097152
  u16* wkvbp = (u16*)(ws + D0 + 12582912ull);         // 3 planes, pl 2097152
  u16* opl   = (u16*)(ws + D0);                       // 3 planes, pl 8388608
  u16* t1b   = (u16*)(ws + D0);
  u16* asb   = (u16*)(ws + D0 + 16777216ull);
  u16* qpl   = (u16*)(ws + D1);                       // 2 planes, pl 12582912
  u16* swp   = (u16*)(ws + D1 + 25165824ull);
  u16* vtp   = (u16*)(ws + D2);                       // 3 planes, pl 8388608
  float* firstb = (float*)(ws + D2);
  u16* h2b   = (u16*)(ws + D2 + 33554432ull);         // @134217728
  u16* wqp   = (u16*)(ws + D3);                       // 3 planes, pl 6291456
  u16* wkvap = (u16*)(ws + D3);                       // 3 planes, pl 1179648
  float* kvr = (float*)(ws + D3 + 7077888ull);
  u16* kpl0  = (u16*)(ws + D3);                       // 2 planes, pl 8388608
  u16* kpl1  = kpl0 + 8388608ull;
  u16* kpe0  = (u16*)(ws + D3 + 33554432ull);
  u16* kpe1  = kpe0 + 262144ull;
  u16* wop   = (u16*)(ws + D3);                       // 3 planes, pl 4194304
  // expert stage (deterministic sizes)
  u16* h2g   = (u16*)(ws + 0);                        //  67,108,864 B (16384x2048 bf16)
  u16* yout  = (u16*)(ws + 0);                        //  67,108,864 B (over h2g: dead after gate GEMM)
  u16* y1e   = (u16*)(ws + 67108864ull);              //  33,554,432 B
  u16* aee   = (u16*)(ws + 100663296ull);             //  33,554,432 B
  u16* wexp  = (u16*)(ws + 134217728ull);             //  50,331,648 B (ends 184,549,376)
  float* cosT = (float*)(ws + SM);
  float* sinT = (float*)(ws + SM + 262144ull);
  int*   idxb = (int*)(ws + SM + 524288ull);
  float* gw4b = (float*)(ws + SM + 589824ull);
  int*   listb= (int*)(ws + SM + 655360ull);
  float* gwsb = (float*)(ws + SM + 720896ull);
  int*   cntb = (int*)(ws + SM + 786432ull);
  int*   curb = (int*)(ws + SM + 786688ull);
  int*   baseb= (int*)(ws + SM + 786944ull);
  int*   tbb  = (int*)(ws + SM + 787200ull);
  int*   slotb= (int*)(ws + SM + 787456ull);          // 65,536 B

  const size_t PL_TD = (size_t)TKN * DIM;  // 8388608

  hipMemsetAsync(cntb, 0, 256, stream);
  rope_table<<<dim3(256), 256, 0, stream>>>(cosT, sinT, sp);
  rmsnorm3<<<dim3(TKN), 256, 0, stream>>>(x, norm_w, hpl);

  // q = h @ wq^T (fused RoPE + x2-split out); 3 products
  split3<<<dim3(1024), 256, 0, stream>>>(wq, wqp, (size_t)3072 * 2048, 6291456ull);
  gemm_f<EF_QROPE, AM_DIR, 3><<<dim3(32, 24), 256, 0, stream>>>(
      hpl, wqp, nullptr, TKN, 3072, 2048, PL_TD, 6291456ull,
      nullptr, nullptr, nullptr, sinT, nullptr, qpl, qpl + 12582912ull, nullptr, cosT, nullptr);

  // kv = h @ wkv_a^T (f32-grade, 6 products)
  split3<<<dim3(512), 256, 0, stream>>>(wkv_a, wkvap, (size_t)576 * 2048, 1179648ull);
  gemm_f<EF_F32, AM_DIR, 6><<<dim3(32, 5), 256, 0, stream>>>(
      hpl, wkvap, kvr, TKN, 576, 2048, PL_TD, 1179648ull,
      nullptr, nullptr, nullptr, nullptr, nullptr, nullptr, nullptr, nullptr, nullptr, nullptr);

  kv_split<<<dim3(TKN), 256, 0, stream>>>(kvr, kvnw, cpl, kpe0, kpe1, cosT, sinT);

  // k_nope/v = c @ wkv_b^T (split K planes + transposed V planes)
  split3<<<dim3(1024), 256, 0, stream>>>(wkv_b, wkvbp, (size_t)4096 * 512, 2097152ull);
  gemm_f<EF_KV, AM_DIR, 6><<<dim3(32, 32), 256, 0, stream>>>(
      cpl, wkvbp, nullptr, TKN, 4096, 512, 2097152ull, 2097152ull,
      nullptr, nullptr, nullptr, nullptr, nullptr, kpl0, kpl1, vtp, nullptr, nullptr);

  attn3<<<dim3(16, 32), 256, 0, stream>>>(qpl, qpl + 12582912ull, kpl0, kpl1,
      kpe0, kpe1, vtp, opl, 1.f / sqrtf(192.f));

  // first = o @ wo^T + x
  split3<<<dim3(1024), 256, 0, stream>>>(wo, wop, (size_t)2048 * 2048, 4194304ull);
  gemm_f<EF_RES, AM_DIR, 6><<<dim3(32, 16), 256, 0, stream>>>(
      opl, wop, firstb, TKN, 2048, 2048, PL_TD, 4194304ull,
      nullptr, nullptr, nullptr, x, nullptr, nullptr, nullptr, nullptr, nullptr, nullptr);

  gate_topk<<<dim3(TKN), 256, 0, stream>>>(firstb, norm_w, gatew, gateb, idxb, gw4b, cntb, h2b);
  prefix12<<<dim3(1), 64, 0, stream>>>(cntb, baseb, curb, tbb);
  fill_lists<<<dim3(16), 256, 0, stream>>>(idxb, baseb, curb, listb, gw4b, gwsb, slotb);

  // shared expert (84-VGPR template); down-proj adds `first` (out = ys + first)
  cvt1<<<dim3(1024), 256, 0, stream>>>(sw1, swp, (size_t)2048 * 2048);
  cvt1<<<dim3(1024), 256, 0, stream>>>(sw3, swp + 4194304ull, (size_t)2048 * 2048);
  cvt1<<<dim3(1024), 256, 0, stream>>>(sw2, swp + 8388608ull, (size_t)2048 * 2048);
  gemm_f<EF_BF16, AM_DIR, 1><<<dim3(32, 16), 256, 0, stream>>>(
      h2b, swp, t1b, TKN, 2048, 2048, 0, 0,
      nullptr, nullptr, nullptr, nullptr, nullptr, nullptr, nullptr, nullptr, nullptr, nullptr);
  gemm_f<EF_SILU, AM_DIR, 1><<<dim3(32, 16), 256, 0, stream>>>(
      h2b, swp + 4194304ull, asb, TKN, 2048, 2048, 0, 0,
      nullptr, nullptr, nullptr, t1b, nullptr, nullptr, nullptr, nullptr, nullptr, nullptr);
  gemm_f<EF_RES, AM_DIR, 1><<<dim3(32, 16), 256, 0, stream>>>(
      asb, swp + 8388608ull, out, TKN, 2048, 2048, 0, 0,
      nullptr, nullptr, nullptr, firstb, nullptr, nullptr, nullptr, nullptr, nullptr, nullptr);

  // routed experts: tile-compacted 1-D grids; down-proj de-atomized
  gather_h2<<<dim3(TKN * 4), 256, 0, stream>>>(h2b, listb, h2g);
  cvt1<<<dim3(2048), 256, 0, stream>>>(w1, wexp, (size_t)12 * 1024 * 2048);
  gemm_f<EF_BF16, AM_TIL, 1><<<dim3(12 * 32 * 8), 256, 0, stream>>>(
      h2g, wexp, y1e, 0, 1024, 2048, 0, 0,
      listb, baseb, cntb, nullptr, nullptr, nullptr, nullptr, nullptr, nullptr, tbb);
  cvt1<<<dim3(2048), 256, 0, stream>>>(w3, wexp, (size_t)12 * 1024 * 2048);
  gemm_f<EF_SILU, AM_TIL, 1><<<dim3(12 * 32 * 8), 256, 0, stream>>>(
      h2g, wexp, aee, 0, 1024, 2048, 0, 0,
      listb, baseb, cntb, y1e, nullptr, nullptr, nullptr, nullptr, nullptr, tbb);
  cvt1<<<dim3(2048), 256, 0, stream>>>(w2, wexp, (size_t)12 * 2048 * 1024);
  gemm_f<EF_BF16, AM_TIL, 1><<<dim3(12 * 32 * 16), 256, 0, stream>>>(
      aee, wexp, yout, 0, 2048, 1024, 0, 0,
      listb, baseb, cntb, nullptr, nullptr, nullptr, nullptr, nullptr, nullptr, tbb);
  final_combine<<<dim3(TKN), 256, 0, stream>>>(out, yout, gw4b, slotb);
}